// Round 4
// baseline (2682.039 us; speedup 1.0000x reference)
//
#include <hip/hip_runtime.h>
#include <cmath>

#define HID 51
#define NG  204      // 4*HID gates per cell
#define BATCH 256
#define BLK 1024     // 16 waves (max workgroup on gfx950)

// One block per batch element.
// Roles: 0 = layer0 full row (wx + Whh1 vs h0, t=tau)
//        1 = layer1 Wih vs h0 (t=tau-1)   2 = layer1 Whh vs h1 (t=tau-1)
//        3 = layer2 Wih vs h1 (t=tau-2)   4 = layer2 Whh vs h2 (t=tau-2)
//        5 = output Wl vs h2 (t=tau-3)
// Waves 0..14: role = wave/3, gates (wave%3)*64 + lane = 0..191.
//   Phase A via register broadcast: lane reads ONE h element (ds_read_b32),
//   then 51 x { v_readlane -> sgpr, v_fmac } — no LDS flood, weights in VGPRs.
// Wave 15: gates 192..203 of all 5 roles (lanes 0..59) + output (lane 60),
//   per-lane h-source -> old float4-from-LDS path (1 wave, cheap).
// Phase B: tids 0..152 do the 3 cell updates (c in register), h -> LDS;
//   tid 1020 stores the output slot.

__device__ __forceinline__ float rdlane(float v, int l) {
    return __int_as_float(__builtin_amdgcn_readlane(__float_as_int(v), l));
}

__global__ __launch_bounds__(BLK, 4)
void lstm3_kernel(const float* __restrict__ x,
                  const float* __restrict__ Wih1, const float* __restrict__ Whh1,
                  const float* __restrict__ bih1, const float* __restrict__ bhh1,
                  const float* __restrict__ Wih,  const float* __restrict__ Whh,
                  const float* __restrict__ bih,  const float* __restrict__ bhh,
                  const float* __restrict__ Wl,   const float* __restrict__ bl,
                  float* __restrict__ out, int T)
{
    const int b    = blockIdx.x;
    const int tid  = threadIdx.x;
    const int wave = tid >> 6;
    const int lane = tid & 63;

    __shared__ __align__(16) float xbuf[2048];
    __shared__ __align__(16) float hbuf[3][64];   // rows zero-padded past 50
    __shared__ __align__(16) float gP[6][208];    // rows 0..4 partials, row 5 zeros
    __shared__ float oslot[2];                    // [0]=output dot, [1]=sink

    for (int i = tid; i < T; i += BLK) xbuf[i] = x[(size_t)b * T + i];
    if (tid < 192) ((float*)hbuf)[tid] = 0.f;
    if (tid < 208) gP[5][tid] = 0.f;

    // ---------------- role assignment ----------------
    int role = -1, gate = 0;
    if (wave < 15)       { role = wave / 3; gate = (wave - 3 * (wave / 3)) * 64 + lane; }
    else if (lane < 60)  { role = lane / 12; gate = 192 + (lane - 12 * (lane / 12)); }
    else if (lane == 60) { role = 5; }

    float w[52];
    #pragma unroll
    for (int j = 0; j < 52; ++j) w[j] = 0.f;
    float wx = 0.f, bias = 0.f;
    int t_off = 1 << 20;
    const float* hsrc = hbuf[0];
    float* gdst = &oslot[1];

    if (role == 0) {
        wx   = Wih1[gate];
        bias = bih1[gate] + bhh1[gate];
        const float* row = Whh1 + (size_t)gate * 51;
        #pragma unroll
        for (int j = 0; j < 51; ++j) w[j] = row[j];
        hsrc = hbuf[0]; gdst = &gP[0][gate]; t_off = 0;
    } else if (role >= 1 && role <= 4) {
        const int  l   = (role - 1) >> 1;     // 0 or 1
        const bool isA = (role & 1) != 0;     // roles 1,3 = Wih half (carries bias)
        const float* row = (isA ? Wih : Whh) + (size_t)(l * NG + gate) * 51;
        #pragma unroll
        for (int j = 0; j < 51; ++j) w[j] = row[j];
        if (isA) bias = bih[l * NG + gate] + bhh[l * NG + gate];
        hsrc = hbuf[role >> 1];               // 1->h0, 2->h1, 3->h1, 4->h2
        gdst = &gP[role][gate];
        t_off = (role + 1) >> 1;              // 1,1,2,2
    } else if (role == 5) {
        bias = bl[0];
        #pragma unroll
        for (int j = 0; j < 51; ++j) w[j] = Wl[j];
        hsrc = hbuf[2]; gdst = &oslot[0]; t_off = 3;
    }
    w[51] = 0.f;

    // phase-B role
    const bool is_cell = (tid < 3 * HID);
    int cl = 0, cu = 0;
    const float *s1 = gP[0], *s2 = gP[5];
    if (is_cell) {
        cl = tid / HID; cu = tid - cl * HID;
        if      (cl == 1) { s1 = gP[1]; s2 = gP[2]; }
        else if (cl == 2) { s1 = gP[3]; s2 = gP[4]; }
    }

    float c_state = 0.f;
    __syncthreads();

    const int TICKS = T + 3;
    for (int tau = 0; tau < TICKS; ++tau) {
        // ---------------- phase A ----------------
        if (wave < 15) {
            const int  t    = tau - t_off;            // wave-uniform
            const bool pred = (unsigned)t < (unsigned)T;
            const float hown = hsrc[lane];            // one ds_read_b32 per wave
            float acc = fmaf(wx, xbuf[pred ? t : 0], bias);
            #pragma unroll
            for (int j = 0; j < 51; ++j)
                acc = fmaf(w[j], rdlane(hown, j), acc);
            if (pred) *gdst = acc;
        } else if (role >= 0) {
            const int  t    = tau - t_off;            // per-lane
            const bool pred = (unsigned)t < (unsigned)T;
            float acc0 = fmaf(wx, xbuf[pred ? t : 0], bias);
            float acc1 = 0.f;
            const float4* hp = (const float4*)hsrc;
            #pragma unroll
            for (int j4 = 0; j4 < 13; ++j4) {
                const float4 h4 = hp[j4];
                const float s = w[4*j4+0]*h4.x + w[4*j4+1]*h4.y
                              + w[4*j4+2]*h4.z + w[4*j4+3]*h4.w;
                if (j4 & 1) acc1 += s; else acc0 += s;
            }
            if (pred) *gdst = acc0 + acc1;
        }
        __syncthreads();
        // ---------------- phase B ----------------
        if (is_cell) {
            const int t = tau - cl;
            if ((unsigned)t < (unsigned)T) {
                const float gi = s1[cu]         + s2[cu];
                const float gf = s1[HID + cu]   + s2[HID + cu];
                const float gg = s1[2*HID + cu] + s2[2*HID + cu];
                const float go = s1[3*HID + cu] + s2[3*HID + cu];
                const float si = 1.f / (1.f + expf(-gi));
                const float sf = 1.f / (1.f + expf(-gf));
                const float so = 1.f / (1.f + expf(-go));
                const float c  = sf * c_state + si * tanhf(gg);
                c_state = c;
                hbuf[cl][cu] = so * tanhf(c);
            }
        } else if (tid == 1020) {
            const int t = tau - 3;
            if ((unsigned)t < (unsigned)T) out[(size_t)b * T + t] = oslot[0];
        }
        __syncthreads();
    }
}

extern "C" void kernel_launch(void* const* d_in, const int* in_sizes, int n_in,
                              void* d_out, int out_size, void* d_ws, size_t ws_size,
                              hipStream_t stream) {
    const float* x    = (const float*)d_in[0];
    const float* Wih1 = (const float*)d_in[1];
    const float* Whh1 = (const float*)d_in[2];
    const float* bih1 = (const float*)d_in[3];
    const float* bhh1 = (const float*)d_in[4];
    const float* Wih  = (const float*)d_in[5];
    const float* Whh  = (const float*)d_in[6];
    const float* bih  = (const float*)d_in[7];
    const float* bhh  = (const float*)d_in[8];
    const float* Wl   = (const float*)d_in[9];
    const float* bl   = (const float*)d_in[10];
    float* out = (float*)d_out;

    const int T = in_sizes[0] / BATCH;   // 2048
    lstm3_kernel<<<BATCH, BLK, 0, stream>>>(x, Wih1, Whh1, bih1, bhh1,
                                            Wih, Whh, bih, bhh, Wl, bl, out, T);
}

// Round 5
// 1760.212 us; speedup vs baseline: 1.5237x; 1.5237x over previous
//
#include <hip/hip_runtime.h>
#include <cmath>

#define HID 51
#define NG  204      // 4*HID gates per cell
#define BATCH 256
#define BLK 1024     // 16 waves (max workgroup on gfx950)

typedef _Float16 half2_t __attribute__((ext_vector_type(2)));

// One block per batch element. 1021 "row-dot" threads, ONE uniform phase-A path:
//   tid    0..203 : layer0 gate g = bias + wx*x[t] + Whh1[g,:].h0   (t = tau)
//   tid  204..407 : layer1 partial A = bias + Wih[0][g,:].h0        (t = tau-1)
//   tid  408..611 : layer1 partial B =        Whh[0][g,:].h1        (t = tau-1)
//   tid  612..815 : layer2 partial A = bias + Wih[1][g,:].h1        (t = tau-2)
//   tid  816..1019: layer2 partial B =        Whh[1][g,:].h2        (t = tau-2)
//   tid 1020      : output = bl + Wl.h2                             (t = tau-3)
// Weights live in 26 packed-fp16 VGPRs per thread (v_dot2_f32_f16, fp32 acc).
// h is stored in LDS as fp16 (rows padded to 64 with zeros). c stays fp32.
// NOTE: no min-occupancy in __launch_bounds__ — tight bounds made the
// allocator AGPR-spill the weight array in rounds 1-4 (VGPR_Count=48).

__global__ __launch_bounds__(BLK)
void lstm3_kernel(const float* __restrict__ x,
                  const float* __restrict__ Wih1, const float* __restrict__ Whh1,
                  const float* __restrict__ bih1, const float* __restrict__ bhh1,
                  const float* __restrict__ Wih,  const float* __restrict__ Whh,
                  const float* __restrict__ bih,  const float* __restrict__ bhh,
                  const float* __restrict__ Wl,   const float* __restrict__ bl,
                  float* __restrict__ out, int T)
{
    const int b   = blockIdx.x;
    const int tid = threadIdx.x;

    __shared__ __align__(16) float    xbuf[2048];
    __shared__ __align__(16) _Float16 hb[3][64];   // fp16 h rows, zero-padded past 50
    __shared__ __align__(16) float    gP[6][208];  // rows 0..4 partials, row 5 zeros
    __shared__ float oslot[2];                     // [0]=output dot, [1]=sink

    for (int i = tid; i < T; i += BLK) xbuf[i] = x[(size_t)b * T + i];
    if (tid < 96)  ((float*)hb)[tid] = 0.f;        // 96 dwords = 192 halves
    if (tid < 208) gP[5][tid] = 0.f;               // permanent zero partial row

    // ---------------- role setup ----------------
    const float* row = nullptr;
    float wx = 0.f, bias = 0.f;
    int t_off = 1 << 20;
    const _Float16* hsrc = hb[0];
    float* gdst = &oslot[1];

    if (tid < NG) {                                   // layer0 full row
        const int g = tid;
        wx   = Wih1[g];
        bias = bih1[g] + bhh1[g];
        row  = Whh1 + (size_t)g * 51;
        hsrc = hb[0]; gdst = &gP[0][g]; t_off = 0;
    } else if (tid < 2 * NG) {                        // layer1 A: Wih vs h0
        const int g = tid - NG;
        bias = bih[g] + bhh[g];
        row  = Wih + (size_t)g * 51;
        hsrc = hb[0]; gdst = &gP[1][g]; t_off = 1;
    } else if (tid < 3 * NG) {                        // layer1 B: Whh vs h1
        const int g = tid - 2 * NG;
        row  = Whh + (size_t)g * 51;
        hsrc = hb[1]; gdst = &gP[2][g]; t_off = 1;
    } else if (tid < 4 * NG) {                        // layer2 A: Wih vs h1
        const int g = tid - 3 * NG;
        bias = bih[NG + g] + bhh[NG + g];
        row  = Wih + (size_t)(NG + g) * 51;
        hsrc = hb[1]; gdst = &gP[3][g]; t_off = 2;
    } else if (tid < 5 * NG) {                        // layer2 B: Whh vs h2
        const int g = tid - 4 * NG;
        row  = Whh + (size_t)(NG + g) * 51;
        hsrc = hb[2]; gdst = &gP[4][g]; t_off = 2;
    } else if (tid == 5 * NG) {                       // output: Wl vs h2
        bias = bl[0];
        row  = Wl;
        hsrc = hb[2]; gdst = &oslot[0]; t_off = 3;
    }

    // pack weight row into 26 half2 VGPRs
    half2_t w2[26];
    #pragma unroll
    for (int j = 0; j < 26; ++j) w2[j] = half2_t{(_Float16)0.f, (_Float16)0.f};
    if (row) {
        #pragma unroll
        for (int j = 0; j < 25; ++j)
            w2[j] = half2_t{(_Float16)row[2*j], (_Float16)row[2*j+1]};
        w2[25] = half2_t{(_Float16)row[50], (_Float16)0.f};
    }

    // phase-B role
    const bool is_cell = (tid < 3 * HID);
    int cl = 0, cu = 0;
    const float *s1 = gP[0], *s2 = gP[5];
    if (is_cell) {
        cl = tid / HID; cu = tid - cl * HID;
        if      (cl == 1) { s1 = gP[1]; s2 = gP[2]; }
        else if (cl == 2) { s1 = gP[3]; s2 = gP[4]; }
    }

    float c_state = 0.f;
    __syncthreads();

    const int TICKS = T + 3;
    for (int tau = 0; tau < TICKS; ++tau) {
        // ---------------- phase A: uniform fp16 row dots ----------------
        {
            const int  t    = tau - t_off;
            const bool pred = (unsigned)t < (unsigned)T;
            float4 hv[7];
            const float4* hp = (const float4*)hsrc;   // 112 B covers halves 0..55
            #pragma unroll
            for (int k = 0; k < 7; ++k) hv[k] = hp[k];
            const half2_t* hh = (const half2_t*)hv;
            float acc0 = fmaf(wx, xbuf[pred ? t : 0], bias);
            float acc1 = 0.f;
            #pragma unroll
            for (int j = 0; j < 26; ++j) {
                if (j & 1) acc1 = __builtin_amdgcn_fdot2(w2[j], hh[j], acc1, false);
                else       acc0 = __builtin_amdgcn_fdot2(w2[j], hh[j], acc0, false);
            }
            if (pred) *gdst = acc0 + acc1;
        }
        __syncthreads();
        // ---------------- phase B: cell updates ----------------
        if (is_cell) {
            const int t = tau - cl;
            if ((unsigned)t < (unsigned)T) {
                const float gi = s1[cu]         + s2[cu];
                const float gf = s1[HID + cu]   + s2[HID + cu];
                const float gg = s1[2*HID + cu] + s2[2*HID + cu];
                const float go = s1[3*HID + cu] + s2[3*HID + cu];
                const float si = 1.f / (1.f + expf(-gi));
                const float sf = 1.f / (1.f + expf(-gf));
                const float so = 1.f / (1.f + expf(-go));
                const float c  = sf * c_state + si * tanhf(gg);
                c_state = c;
                hb[cl][cu] = (_Float16)(so * tanhf(c));
            }
        } else if (tid == 5 * NG) {
            const int t = tau - 3;
            if ((unsigned)t < (unsigned)T) out[(size_t)b * T + t] = oslot[0];
        }
        __syncthreads();
    }
}

extern "C" void kernel_launch(void* const* d_in, const int* in_sizes, int n_in,
                              void* d_out, int out_size, void* d_ws, size_t ws_size,
                              hipStream_t stream) {
    const float* x    = (const float*)d_in[0];
    const float* Wih1 = (const float*)d_in[1];
    const float* Whh1 = (const float*)d_in[2];
    const float* bih1 = (const float*)d_in[3];
    const float* bhh1 = (const float*)d_in[4];
    const float* Wih  = (const float*)d_in[5];
    const float* Whh  = (const float*)d_in[6];
    const float* bih  = (const float*)d_in[7];
    const float* bhh  = (const float*)d_in[8];
    const float* Wl   = (const float*)d_in[9];
    const float* bl   = (const float*)d_in[10];
    float* out = (float*)d_out;

    const int T = in_sizes[0] / BATCH;   // 2048
    lstm3_kernel<<<BATCH, BLK, 0, stream>>>(x, Wih1, Whh1, bih1, bhh1,
                                            Wih, Whh, bih, bhh, Wl, bl, out, T);
}

// Round 6
// 1679.043 us; speedup vs baseline: 1.5974x; 1.0483x over previous
//
#include <hip/hip_runtime.h>
#include <cmath>

#define HID 51
#define BATCH 256
#define BLK 768       // 3 layer-sections x 256 (12 waves)
#define OUT_TID 204   // layer0 section, unit 51, gt 0 (idle slot) -> output role

typedef _Float16 half2_t __attribute__((ext_vector_type(2)));

// One block per batch element. tid = layer*256 + unit*4 + gt (unit 0..63, valid < 51).
// Each gate thread holds BOTH weight rows packed fp16: wA = Wih row (vs h_{l-1}),
// wB = Whh row (vs h_l); layer0: wA = Whh1 row, wx = Wih1, wB = 0.
// Tick tau: layer l computes timestep t = tau - l. All h reads hit hb[tau&1]
// (written at tick tau-1); h writes go to hb[tau&1^1] -> ONE barrier per tick.
// Gate pre-acts gathered into the gt==0 lane via 3 ds_swizzle (quad xor1/xor2);
// cell update (c in register) + fp16 h write happen in the same wave.
// Output Wl.h2(tau-3)+bl computed by OUT_TID into an LDS ring; wave 3 flushes
// 64 outputs with one coalesced store every 64 ticks (T must be %64, it is 2048).

__device__ __forceinline__ float fsig(float v) {
    return __builtin_amdgcn_rcpf(1.f + __expf(-v));
}
__device__ __forceinline__ float ftanh(float v) {
    const float e = __expf(2.f * v);                    // inf-safe: 1-2/(inf+1)=1
    return fmaf(-2.f, __builtin_amdgcn_rcpf(e + 1.f), 1.f);
}

__global__ __launch_bounds__(BLK)
void lstm3_kernel(const float* __restrict__ x,
                  const float* __restrict__ Wih1, const float* __restrict__ Whh1,
                  const float* __restrict__ bih1, const float* __restrict__ bhh1,
                  const float* __restrict__ Wih,  const float* __restrict__ Whh,
                  const float* __restrict__ bih,  const float* __restrict__ bhh,
                  const float* __restrict__ Wl,   const float* __restrict__ bl,
                  float* __restrict__ out, int T)
{
    const int b    = blockIdx.x;
    const int tid  = threadIdx.x;
    const int layer = tid >> 8;        // 0..2
    const int sub   = tid & 255;
    const int unit  = sub >> 2;        // 0..63 (valid < 51)
    const int gt    = sub & 3;         // 0=i 1=f 2=g 3=o

    __shared__ __align__(16) float    xbuf[2048];
    __shared__ __align__(16) _Float16 hb[2][3][64];   // double-buffered h, rows 128B
    __shared__ __align__(16) float    obuf[128];      // output ring (2 x 64)

    for (int i = tid; i < T; i += BLK) xbuf[i] = x[(size_t)b * T + i];
    if (tid < 192) ((float*)hb)[tid] = 0.f;           // zero both h buffers

    // ---------------- role setup ----------------
    const bool role_out = (tid == OUT_TID);
    const bool is_gate  = (unit < HID);
    const bool is_cell  = is_gate && (gt == 0);

    const float* rowA = nullptr;
    const float* rowB = nullptr;
    float wx = 0.f, bias = 0.f;
    int selA = 0, selB = 0, t_off = layer;
    if (is_gate) {
        const int r = gt * HID + unit;                // PyTorch gate-row index
        if (layer == 0) {
            wx   = Wih1[r];
            bias = bih1[r] + bhh1[r];
            rowA = Whh1 + (size_t)r * 51;
            selA = 0; selB = 0;                       // wB=0, reads harmless
        } else {
            const int gr = (layer - 1) * 204 + r;
            bias = bih[gr] + bhh[gr];
            rowA = Wih + (size_t)gr * 51;
            rowB = Whh + (size_t)gr * 51;
            selA = layer - 1; selB = layer;
        }
    } else if (role_out) {
        bias = bl[0];
        rowA = Wl;
        selA = 2; selB = 2; t_off = 3;
    }

    half2_t wA[26], wB[26];
    #pragma unroll
    for (int j = 0; j < 26; ++j) {
        wA[j] = half2_t{(_Float16)0.f, (_Float16)0.f};
        wB[j] = half2_t{(_Float16)0.f, (_Float16)0.f};
    }
    if (rowA) {
        #pragma unroll
        for (int j = 0; j < 25; ++j)
            wA[j] = half2_t{(_Float16)rowA[2*j], (_Float16)rowA[2*j+1]};
        wA[25] = half2_t{(_Float16)rowA[50], (_Float16)0.f};
    }
    if (rowB) {
        #pragma unroll
        for (int j = 0; j < 25; ++j)
            wB[j] = half2_t{(_Float16)rowB[2*j], (_Float16)rowB[2*j+1]};
        wB[25] = half2_t{(_Float16)rowB[50], (_Float16)0.f};
    }

    float c_state = 0.f;
    __syncthreads();

    const int TICKS = T + 3;
    for (int tau = 0; tau < TICKS; ++tau) {
        const int par = tau & 1;
        const _Float16* rb = &hb[par][0][0];
        const float4* pa = (const float4*)(rb + selA * 64);
        const float4* pb = (const float4*)(rb + selB * 64);
        const int  t    = tau - t_off;
        const bool pred = (unsigned)t < (unsigned)T;

        // ---- dots: 52 x v_dot2_f32_f16, 4 accumulator chains ----
        float4 a4[7], b4[7];
        #pragma unroll
        for (int k = 0; k < 7; ++k) { a4[k] = pa[k]; b4[k] = pb[k]; }
        const half2_t* ha = (const half2_t*)a4;
        const half2_t* hv = (const half2_t*)b4;
        float acc0 = fmaf(wx, xbuf[pred ? t : 0], bias);
        float acc1 = 0.f, acc2 = 0.f, acc3 = 0.f;
        #pragma unroll
        for (int j = 0; j < 26; ++j) {
            if (j & 1) acc1 = __builtin_amdgcn_fdot2(wA[j], ha[j], acc1, false);
            else       acc0 = __builtin_amdgcn_fdot2(wA[j], ha[j], acc0, false);
        }
        #pragma unroll
        for (int j = 0; j < 26; ++j) {
            if (j & 1) acc3 = __builtin_amdgcn_fdot2(wB[j], hv[j], acc3, false);
            else       acc2 = __builtin_amdgcn_fdot2(wB[j], hv[j], acc2, false);
        }
        const float acc = (acc0 + acc1) + (acc2 + acc3);

        // ---- quad gather: lane 4u+0 collects i,f,g,o (unconditional) ----
        const float fpre = __int_as_float(__builtin_amdgcn_ds_swizzle(__float_as_int(acc),  0x041F)); // xor1
        const float gpre = __int_as_float(__builtin_amdgcn_ds_swizzle(__float_as_int(acc),  0x081F)); // xor2
        const float opre = __int_as_float(__builtin_amdgcn_ds_swizzle(__float_as_int(fpre), 0x081F)); // xor2 of xor1

        if (pred) {
            if (is_cell) {
                const float si = fsig(acc);
                const float sf = fsig(fpre);
                const float tg = ftanh(gpre);
                const float so = fsig(opre);
                const float c  = fmaf(sf, c_state, si * tg);
                c_state = c;
                hb[par ^ 1][layer][unit] = (_Float16)(so * ftanh(c));
            } else if (role_out) {
                obuf[t & 127] = acc;                   // t = tau-3
            }
        }
        // ---- coalesced output flush: one 64-wide store per 64 ticks ----
        if ((tid >> 6) == 3 && (tau & 63) == 2 && tau >= 66) {
            const int t0   = tau - 66;                 // multiple of 64
            const int lane = tid & 63;
            out[(size_t)b * T + t0 + lane] = obuf[(t0 & 64) + lane];
        }
        __syncthreads();
    }
}

extern "C" void kernel_launch(void* const* d_in, const int* in_sizes, int n_in,
                              void* d_out, int out_size, void* d_ws, size_t ws_size,
                              hipStream_t stream) {
    const float* x    = (const float*)d_in[0];
    const float* Wih1 = (const float*)d_in[1];
    const float* Whh1 = (const float*)d_in[2];
    const float* bih1 = (const float*)d_in[3];
    const float* bhh1 = (const float*)d_in[4];
    const float* Wih  = (const float*)d_in[5];
    const float* Whh  = (const float*)d_in[6];
    const float* bih  = (const float*)d_in[7];
    const float* bhh  = (const float*)d_in[8];
    const float* Wl   = (const float*)d_in[9];
    const float* bl   = (const float*)d_in[10];
    float* out = (float*)d_out;

    const int T = in_sizes[0] / BATCH;   // 2048 (flush logic assumes T % 64 == 0)
    lstm3_kernel<<<BATCH, BLK, 0, stream>>>(x, Wih1, Whh1, bih1, bhh1,
                                            Wih, Whh, bih, bhh, Wl, bl, out, T);
}